// Round 8
// baseline (231.711 us; speedup 1.0000x reference)
//
#include <hip/hip_runtime.h>

#define OBS 64
#define EXT 20
#define HID 84
#define TT  64
#define BB  16

// ws float offsets (total 172480 floats = ~690 KB)
#define OFF_T1INV 0        // 64x64
#define OFF_XT    4096     // 20x64
#define OFF_NA1   5376     // 20x64
#define OFF_ANT1  6656     // 20x64
#define OFF_ANA1  7936     // 20x64
#define OFF_N     9216     // 84x20
#define OFF_AN    10896    // 84x20
#define OFF_D     12576    // 20x20
#define OFF_DLAST 12976    // 20x20
#define OFF_F     13376    // 20x20
#define OFF_Q     13776    // [b][i][64]
#define OFF_G     79312    // [i][b][20] rhs g (read-only after k_qg)
#define OFF_JG    99792    // [i][20][20] J_i row-major
#define OFF_ZG    125392   // [i][20][20] Z_i = J_i F^T row-major (= FJ^T)
#define OFF_TS    150992   // [i][b][20] solution t
#define OFF_PART  171472   // 1008 partial sums
#define OFF_ICONV OFF_D    // k_factor writes iconv AFTER its last read of D

#define RDLANE(v, l) __uint_as_float(__builtin_amdgcn_readlane((int)__float_as_uint(v), (l)))

__device__ __forceinline__ void ld20(const float* p, float a[20]) {
    const float4* q = (const float4*)p;
    float4 v0 = q[0], v1 = q[1], v2 = q[2], v3 = q[3], v4 = q[4];
    a[0]=v0.x; a[1]=v0.y; a[2]=v0.z; a[3]=v0.w;
    a[4]=v1.x; a[5]=v1.y; a[6]=v1.z; a[7]=v1.w;
    a[8]=v2.x; a[9]=v2.y; a[10]=v2.z; a[11]=v2.w;
    a[12]=v3.x; a[13]=v3.y; a[14]=v3.z; a[15]=v3.w;
    a[16]=v4.x; a[17]=v4.y; a[18]=v4.z; a[19]=v4.w;
}

__device__ __forceinline__ float dot20(const float a[20], const float v[20]) {
    float s0 = 0.f, s1 = 0.f, s2 = 0.f, s3 = 0.f;
    #pragma unroll
    for (int m = 0; m < 20; m += 4) {
        s0 += a[m]     * v[m];
        s1 += a[m + 1] * v[m + 1];
        s2 += a[m + 2] * v[m + 2];
        s3 += a[m + 3] * v[m + 3];
    }
    return (s0 + s1) + (s2 + s3);
}

// ---------------------------------------------------------------------------
// k_prepgj: register-resident 64x64 Gauss-Jordan inverse, ONE wave, zero LDS,
// zero barriers. Lane r owns row r of [Treg | I] in w[64]+wi[64] VGPRs.
// Virtual partial pivoting: argmax via shfl over non-used lanes; pivot row
// broadcast via v_readlane (wave-uniform p). Fully unrolled -> all register
// indices compile-time. Matrix half prunes to c>k; inverse half full-width
// (fill-in follows pivot LANES, not step order). Lane writes T1inv row myk.
// ---------------------------------------------------------------------------
__global__ __launch_bounds__(64, 1) void k_prepgj(const float* __restrict__ C,
                                                  float* __restrict__ ws) {
    int lane = threadIdx.x;
    float w[64], wi[64];
    #pragma unroll
    for (int c = 0; c < 64; ++c) {
        w[c]  = C[lane * HID + c] + (c == lane ? 1e-3f : 0.0f);
        wi[c] = (c == lane) ? 1.0f : 0.0f;
    }

    bool used = false;
    int myk = 0;
    #pragma unroll 64
    for (int k = 0; k < 64; ++k) {
        float a_rk = w[k];
        float v = used ? -1.0f : fabsf(a_rk);
        int idx = lane;
        #pragma unroll
        for (int off = 32; off; off >>= 1) {
            float v2 = __shfl_down(v, off);
            int   i2 = __shfl_down(idx, off);
            if (v2 > v) { v = v2; idx = i2; }
        }
        int p = __shfl(idx, 0);
        float piv = RDLANE(a_rk, p);
        float rp  = 1.0f / piv;
        bool isp  = (lane == p);
        float fc    = isp ? 0.0f : a_rk * rp;
        float coeff = isp ? rp : -fc;
        if (isp) { used = true; myk = k; }
        #pragma unroll
        for (int c = k + 1; c < 64; ++c) {
            float tmp  = RDLANE(w[c], p);
            float base = isp ? 0.0f : w[c];
            w[c] = fmaf(tmp, coeff, base);
        }
        #pragma unroll
        for (int c = 0; c < 64; ++c) {
            float tmp  = RDLANE(wi[c], p);
            float base = isp ? 0.0f : wi[c];
            wi[c] = fmaf(tmp, coeff, base);
        }
    }

    float* dst = ws + OFF_T1INV + myk * 64;
    #pragma unroll
    for (int c = 0; c < 64; c += 4) {
        float4 v4 = make_float4(wi[c], wi[c + 1], wi[c + 2], wi[c + 3]);
        *reinterpret_cast<float4*>(dst + c) = v4;
    }
}

// ---------------------------------------------------------------------------
// k_small: constant-matrix algebra (round-6 proven trailing code verbatim;
// T1inv now read from ws, written by k_prepgj).
// ---------------------------------------------------------------------------
__global__ __launch_bounds__(512) void k_small(const float* __restrict__ A,
                                               const float* __restrict__ C,
                                               float* __restrict__ ws) {
    __shared__ float Xs[64][20];
    __shared__ float Ns[84][20];
    __shared__ float ANs[84][20];
    int tid = threadIdx.x;

    for (int id = tid; id < 64 * 20; id += 512) {
        int r = id / 20, j = id % 20;
        float s = 0.f;
        const float* tr = ws + OFF_T1INV + r * 64;
        for (int c = 0; c < 64; ++c) s += tr[c] * C[c * HID + 64 + j];
        Xs[r][j] = s;
        ws[OFF_XT + j * 64 + r] = s;
    }
    __syncthreads();
    for (int id = tid; id < HID * 20; id += 512) {
        int p = id / 20, j = id % 20;
        float v = (p < 64) ? -Xs[p][j] : ((p - 64) == j ? 1.f : 0.f);
        Ns[p][j] = v;
        ws[OFF_N + id] = v;
    }
    __syncthreads();
    for (int id = tid; id < HID * 20; id += 512) {
        int p = id / 20, j = id % 20;
        float s = 0.f;
        for (int m = 0; m < HID; ++m) s += A[p * HID + m] * Ns[m][j];
        ANs[p][j] = s;
        ws[OFF_AN + id] = s;
    }
    __syncthreads();
    for (int id = tid; id < 400; id += 512) {
        int a = id / 20, b = id % 20;
        float sn = 0.f, sf = 0.f, sg = 0.f;
        for (int p = 0; p < HID; ++p) {
            sn += Ns[p][a] * Ns[p][b];
            sf += Ns[p][a] * ANs[p][b];
            sg += ANs[p][a] * ANs[p][b];
        }
        ws[OFF_F + id]     = sf;
        ws[OFF_D + id]     = sn + sg;
        ws[OFF_DLAST + id] = sn;
    }
    for (int id = tid; id < 20 * 64; id += 512) {
        int j = id / 64, c = id % 64;
        float s1 = 0.f, s2 = 0.f;
        for (int p = 0; p < HID; ++p) {
            float av = A[p * HID + c];
            s1 += Ns[p][j] * av;
            s2 += ANs[p][j] * av;
        }
        ws[OFF_NA1 + id]  = s1;
        ws[OFF_ANA1 + id] = s2;
        ws[OFF_ANT1 + id] = ANs[c][j];
    }
}

// ---------------------------------------------------------------------------
// k_factor (round-7 proven, verbatim)
// ---------------------------------------------------------------------------
__global__ __launch_bounds__(64, 1) void k_factor(float* __restrict__ ws) {
    __shared__ float sD[400], sDl[400], sF[400];
    int lane = threadIdx.x;
    for (int id = lane; id < 400; id += 64) {
        sD[id]  = ws[OFF_D + id];
        sDl[id] = ws[OFF_DLAST + id];
        sF[id]  = ws[OFF_F + id];
    }
    __syncthreads();

    float* Jg = ws + OFF_JG;
    float* Zg = ws + OFF_ZG;

    float Kprev[20];
    #pragma unroll
    for (int r = 0; r < 20; ++r) Kprev[r] = 0.f;
    int iconv = 62;
    for (int i = 0; i < 64; ++i) {
        bool last = (i == 63);
        float w[40];
        #pragma unroll
        for (int r = 0; r < 20; ++r) {
            float v, v2 = 0.f;
            if (lane < 20) {
                float dv = last ? sDl[r * 20 + lane] : sD[r * 20 + lane];
                v  = dv - Kprev[r];
                v2 = sF[r * 20 + lane];
            } else if (lane < 40) {
                v = sF[(lane - 20) * 20 + r];          // F^T block
            } else if (lane < 60) {
                v = (r == lane - 40) ? 1.f : 0.f;      // I block
            } else {
                v = 0.f;
            }
            w[r]      = v;
            w[20 + r] = v2;                             // [F 0 0]
        }
        #pragma unroll
        for (int k = 0; k < 20; ++k) {
            float rp = __builtin_amdgcn_rcpf(RDLANE(w[k], k));
            w[k] *= rp;
            #pragma unroll
            for (int r = 0; r < 40; ++r) {
                if (r == k) continue;
                float ck = RDLANE(w[r], k);
                w[r] -= ck * w[k];
            }
        }
        if (lane >= 40 && lane < 60) {
            int c = lane - 40;
            #pragma unroll
            for (int r = 0; r < 20; ++r) {
                Jg[i * 400 + r * 20 + c] = w[r];                   // J row-major
                if (!last) Zg[i * 400 + c * 20 + r] = -w[20 + r];  // Z = (FJ)^T
            }
        }
        if (last) break;
        float dmax = 0.f, kmax = 0.f;
        int gsel = (20 + lane) << 2;
        #pragma unroll
        for (int r = 0; r < 20; ++r) {
            float kn = -__uint_as_float(__builtin_amdgcn_ds_bpermute(
                gsel, (int)__float_as_uint(w[20 + r])));
            dmax = fmaxf(dmax, fabsf(kn - Kprev[r]));
            kmax = fmaxf(kmax, fabsf(kn));
            Kprev[r] = kn;
        }
        if (i < 62 && __all((lane >= 20) || (dmax <= 1e-7f + 1e-4f * kmax))) {
            iconv = i;
            i = 62;            // next loop iteration is the terminal (63)
        }
    }
    if (lane == 0) ws[OFF_ICONV] = __int_as_float(iconv);
}

// ---------------------------------------------------------------------------
// k_qg (round-7 proven, verbatim)
// ---------------------------------------------------------------------------
__global__ __launch_bounds__(64) void k_qg(const float* __restrict__ x,
                                           float* __restrict__ ws) {
    int i = blockIdx.x, b = blockIdx.y, r = threadIdx.x;
    __shared__ float yv[3][64];
    __shared__ float qs[3][64];
    yv[1][r] = x[(b * TT + i) * 64 + r];
    yv[0][r] = (i > 0)  ? x[(b * TT + i - 1) * 64 + r] : 0.f;
    yv[2][r] = (i < 63) ? x[(b * TT + i + 1) * 64 + r] : 0.f;
    __syncthreads();
    const float* Ti = ws + OFF_T1INV + r * 64;
    float q0 = 0.f, q1 = 0.f, q2 = 0.f;
    for (int c = 0; c < 64; ++c) {
        float t = Ti[c];
        q0 += t * yv[0][c];
        q1 += t * yv[1][c];
        q2 += t * yv[2][c];
    }
    qs[0][r] = q0; qs[1][r] = q1; qs[2][r] = q2;
    ws[OFF_Q + (b * TT + i) * 64 + r] = q1;
    __syncthreads();
    if (r < 20) {
        const float* xt = ws + OFF_XT   + r * 64;
        const float* na = ws + OFF_NA1  + r * 64;
        const float* at = ws + OFF_ANT1 + r * 64;
        const float* aa = ws + OFF_ANA1 + r * 64;
        float s = 0.f;
        if (i < 63) {
            for (int c = 0; c < 64; ++c)
                s += xt[c] * qs[1][c] + na[c] * qs[0][c] + at[c] * qs[2][c] - aa[c] * qs[1][c];
        } else {
            for (int c = 0; c < 64; ++c)
                s += xt[c] * qs[1][c] + na[c] * qs[0][c];
        }
        ws[OFF_G + (i * 16 + b) * 20 + r] = s;
    }
}

// ---------------------------------------------------------------------------
// k_sweeps (round-7 proven, verbatim)
// ---------------------------------------------------------------------------
__global__ __launch_bounds__(64, 1) void k_sweeps(float* __restrict__ ws) {
    __shared__ float rh[TT][2][20];   // r~ history per batch-half
    __shared__ float th[2][20];       // rolling t
    int lane = threadIdx.x;
    int bh   = lane >> 5;
    int b    = (blockIdx.x << 1) + bh;
    int j    = lane & 31;
    int jj   = (j < 20) ? j : 0;
    bool actj = (j < 20);

    int icv = __float_as_int(ws[OFF_ICONV]);
    const float* G  = ws + OFF_G;
    const float* Jg = ws + OFF_JG;
    const float* Zg = ws + OFF_ZG;
    float* TS = ws + OFF_TS;

    float Mrow[20];                       // FJ_infty row jj = Z_infty col jj
    #pragma unroll
    for (int m = 0; m < 20; ++m) Mrow[m] = Zg[icv * 400 + m * 20 + jj];
    float Jr[20], Zr[20], J63r[20];
    ld20(Jg + icv * 400 + jj * 20, Jr);
    ld20(Zg + icv * 400 + jj * 20, Zr);
    ld20(Jg + 63 * 400 + jj * 20, J63r);

    float rt = 0.f, gnext = 0.f;
    if (actj) {
        rt    = G[(0 * 16 + b) * 20 + j];
        rh[0][bh][j] = rt;
        gnext = G[(1 * 16 + b) * 20 + j];
    }
    for (int i = 1; i < TT; ++i) {
        float rv[20];
        ld20(&rh[i - 1][bh][0], rv);
        float s;
        if (i - 1 < icv) {
            float fr[20];
            #pragma unroll
            for (int m = 0; m < 20; ++m) fr[m] = Zg[(i - 1) * 400 + m * 20 + jj];
            s = gnext + dot20(fr, rv);
        } else {
            s = gnext + dot20(Mrow, rv);
        }
        rt = s;
        if (actj) {
            rh[i][bh][j] = rt;
            gnext = (i + 1 < TT) ? G[((i + 1) * 16 + b) * 20 + j] : 0.f;
        }
    }

    {
        float rv[20];
        ld20(&rh[63][bh][0], rv);
        float tn = dot20(J63r, rv);
        if (actj) {
            TS[(63 * 16 + b) * 20 + j] = tn;
            th[bh][j] = tn;
        }
        for (int i = 62; i >= 0; --i) {
            float rvi[20], tv[20];
            ld20(&rh[i][bh][0], rvi);
            ld20(&th[bh][0], tv);
            float t;
            if (i < icv) {
                float jr[20], zr[20];
                ld20(Jg + i * 400 + jj * 20, jr);
                ld20(Zg + i * 400 + jj * 20, zr);
                t = dot20(jr, rvi) + dot20(zr, tv);
            } else {
                t = dot20(Jr, rvi) + dot20(Zr, tv);
            }
            if (actj) {
                TS[(i * 16 + b) * 20 + j] = t;
                th[bh][j] = t;
            }
        }
    }
}

// ---------------------------------------------------------------------------
// k_loss (proven, verbatim)
// ---------------------------------------------------------------------------
__global__ __launch_bounds__(128) void k_loss(const float* __restrict__ A,
                                              float* __restrict__ ws) {
    int i = blockIdx.x + 1, b = blockIdx.y, tid = threadIdx.x;
    __shared__ float ti[20], tm[20], qi[64], qm[64];
    __shared__ float red[128];
    if (tid < 20) {
        ti[tid] = ws[OFF_TS + (i * 16 + b) * 20 + tid];
        tm[tid] = ws[OFF_TS + ((i - 1) * 16 + b) * 20 + tid];
    }
    if (tid < 64) {
        qi[tid] = ws[OFF_Q + (b * TT + i) * 64 + tid];
        qm[tid] = ws[OFF_Q + (b * TT + i - 1) * 64 + tid];
    }
    __syncthreads();
    float e = 0.f;
    if (tid < HID) {
        int p = tid;
        float s = (p < 64) ? qi[p] : 0.f;
        const float* Np  = ws + OFF_N  + p * 20;
        const float* ANp = ws + OFF_AN + p * 20;
        for (int j = 0; j < 20; ++j) s += Np[j] * ti[j] - ANp[j] * tm[j];
        const float* Ar = A + p * HID;
        for (int c = 0; c < 64; ++c) s -= Ar[c] * qm[c];
        e = s * s;
    }
    red[tid] = e;
    __syncthreads();
    for (int off = 64; off; off >>= 1) {
        if (tid < off) red[tid] += red[tid + off];
        __syncthreads();
    }
    if (tid == 0) ws[OFF_PART + b * 63 + (i - 1)] = red[0];
}

// ---------------------------------------------------------------------------
// k_reduce (proven, verbatim)
// ---------------------------------------------------------------------------
__global__ __launch_bounds__(256) void k_reduce(const float* __restrict__ ws,
                                                float* __restrict__ out) {
    __shared__ float red[256];
    int tid = threadIdx.x;
    float s = 0.f;
    for (int id = tid; id < BB * 63; id += 256) s += ws[OFF_PART + id];
    red[tid] = s;
    __syncthreads();
    for (int off = 128; off; off >>= 1) {
        if (tid < off) red[tid] += red[tid + off];
        __syncthreads();
    }
    if (tid == 0) out[0] = red[0] / (float)(BB * (TT - 1) * HID);
}

extern "C" void kernel_launch(void* const* d_in, const int* in_sizes, int n_in,
                              void* d_out, int out_size, void* d_ws, size_t ws_size,
                              hipStream_t stream) {
    (void)in_sizes; (void)n_in; (void)out_size; (void)ws_size;
    const float* x = (const float*)d_in[0];
    const float* A = (const float*)d_in[1];
    const float* C = (const float*)d_in[2];
    float* ws  = (float*)d_ws;
    float* out = (float*)d_out;

    k_prepgj<<<dim3(1),          dim3(64),  0, stream>>>(C, ws);
    k_small <<<dim3(1),          dim3(512), 0, stream>>>(A, C, ws);
    k_factor<<<dim3(1),          dim3(64),  0, stream>>>(ws);
    k_qg    <<<dim3(TT, BB),     dim3(64),  0, stream>>>(x, ws);
    k_sweeps<<<dim3(8),          dim3(64),  0, stream>>>(ws);
    k_loss  <<<dim3(TT - 1, BB), dim3(128), 0, stream>>>(A, ws);
    k_reduce<<<dim3(1),          dim3(256), 0, stream>>>(ws, out);
}

// Round 9
// 185.898 us; speedup vs baseline: 1.2464x; 1.2464x over previous
//
#include <hip/hip_runtime.h>

#define OBS 64
#define EXT 20
#define HID 84
#define TT  64
#define BB  16

// ws float offsets (total 172480 floats = ~690 KB)
#define OFF_T1INV 0        // 64x64
#define OFF_XT    4096     // 20x64
#define OFF_NA1   5376     // 20x64
#define OFF_ANT1  6656     // 20x64
#define OFF_ANA1  7936     // 20x64
#define OFF_N     9216     // 84x20
#define OFF_AN    10896    // 84x20
#define OFF_D     12576    // 20x20
#define OFF_DLAST 12976    // 20x20
#define OFF_F     13376    // 20x20
#define OFF_Q     13776    // [b][i][64]
#define OFF_G     79312    // [i][b][20] rhs g (read-only after k_qg)
#define OFF_JG    99792    // [i][20][20] J_i row-major
#define OFF_ZG    125392   // [i][20][20] Z_i = J_i F^T row-major (= FJ^T)
#define OFF_TS    150992   // [i][b][20] solution t
#define OFF_PART  171472   // 1008 partial sums
#define OFF_ICONV OFF_D    // k_factor writes iconv AFTER its last read of D

#define RDLANE(v, l) __uint_as_float(__builtin_amdgcn_readlane((int)__float_as_uint(v), (l)))

__device__ __forceinline__ void ld20(const float* p, float a[20]) {
    const float4* q = (const float4*)p;
    float4 v0 = q[0], v1 = q[1], v2 = q[2], v3 = q[3], v4 = q[4];
    a[0]=v0.x; a[1]=v0.y; a[2]=v0.z; a[3]=v0.w;
    a[4]=v1.x; a[5]=v1.y; a[6]=v1.z; a[7]=v1.w;
    a[8]=v2.x; a[9]=v2.y; a[10]=v2.z; a[11]=v2.w;
    a[12]=v3.x; a[13]=v3.y; a[14]=v3.z; a[15]=v3.w;
    a[16]=v4.x; a[17]=v4.y; a[18]=v4.z; a[19]=v4.w;
}

__device__ __forceinline__ float dot20(const float a[20], const float v[20]) {
    float s0 = 0.f, s1 = 0.f, s2 = 0.f, s3 = 0.f;
    #pragma unroll
    for (int m = 0; m < 20; m += 4) {
        s0 += a[m]     * v[m];
        s1 += a[m + 1] * v[m + 1];
        s2 += a[m + 2] * v[m + 2];
        s3 += a[m + 3] * v[m + 3];
    }
    return (s0 + s1) + (s2 + s3);
}

// ---------------------------------------------------------------------------
// k_prep: T1inv via 2x2 block-Schur inversion. Wave 0 runs two 32x32
// register-resident GJ inversions with virtual partial pivoting (w[32]+wi[32]
// = 64 VGPR/lane -- fits, unlike R8's 64x64 which spilled). All 512 threads
// do the six 32x32 matmuls. Then the proven constant-matrix tail (k_small).
//   Treg = [[P,Q],[R,S]]; Pinv; W=R*Pinv; V=Pinv*Q; Sc=S-W*Q; Scinv;
//   X1=Scinv*W; X2=V*Scinv; T1inv=[[Pinv+V*X1, -X2],[-X1, Scinv]]
// ---------------------------------------------------------------------------
__global__ __launch_bounds__(512) void k_prep(const float* __restrict__ A,
                                              const float* __restrict__ C,
                                              float* __restrict__ ws) {
    __shared__ float sPinv[1024], sW[1024], sV[1024], sSc[1024];
    __shared__ float sScinv[1024], sX1[1024], sX2[1024];
    __shared__ float Xs[64][20];
    __shared__ float Ns[84][20];
    __shared__ float ANs[84][20];
    int tid = threadIdx.x, wave = tid >> 6, lane = tid & 63;

    // ---- GJ1: Pinv (wave 0, lanes 0-31) ----
    if (wave == 0 && lane < 32) {
        float w[32], wi[32];
        #pragma unroll
        for (int c = 0; c < 32; ++c) {
            w[c]  = C[lane * HID + c] + (c == lane ? 1e-3f : 0.0f);
            wi[c] = (c == lane) ? 1.0f : 0.0f;
        }
        bool used = false; int myk = 0;
        #pragma unroll
        for (int k = 0; k < 32; ++k) {
            float a_rk = w[k];
            float v = used ? -1.0f : fabsf(a_rk);
            int idx = lane;
            #pragma unroll
            for (int off = 16; off; off >>= 1) {
                float v2 = __shfl_down(v, off, 32);
                int   i2 = __shfl_down(idx, off, 32);
                if (v2 > v) { v = v2; idx = i2; }
            }
            int p = __shfl(idx, 0, 32);
            float piv = RDLANE(a_rk, p);
            float rp  = 1.0f / piv;
            bool isp  = (lane == p);
            float coeff = isp ? rp : -(a_rk * rp);
            if (isp) { used = true; myk = k; }
            #pragma unroll
            for (int c = k + 1; c < 32; ++c) {
                float tmp = RDLANE(w[c], p);
                w[c] = fmaf(tmp, coeff, isp ? 0.0f : w[c]);
            }
            #pragma unroll
            for (int c = 0; c < 32; ++c) {
                float tmp = RDLANE(wi[c], p);
                wi[c] = fmaf(tmp, coeff, isp ? 0.0f : wi[c]);
            }
        }
        #pragma unroll
        for (int c = 0; c < 32; ++c) sPinv[myk * 32 + c] = wi[c];
    }
    __syncthreads();

    // ---- W = R*Pinv ; V = Pinv*Q ----
    for (int id = tid; id < 2048; id += 512) {
        int sel = id >> 10, rc = id & 1023, r = rc >> 5, c = rc & 31;
        float s = 0.f;
        if (sel == 0) {
            for (int m = 0; m < 32; ++m) s += C[(32 + r) * HID + m] * sPinv[m * 32 + c];
            sW[rc] = s;
        } else {
            for (int m = 0; m < 32; ++m) s += sPinv[r * 32 + m] * C[m * HID + 32 + c];
            sV[rc] = s;
        }
    }
    __syncthreads();

    // ---- Sc = S - W*Q ----
    for (int id = tid; id < 1024; id += 512) {
        int r = id >> 5, c = id & 31;
        float s = C[(32 + r) * HID + 32 + c] + (r == c ? 1e-3f : 0.f);
        for (int m = 0; m < 32; ++m) s -= sW[r * 32 + m] * C[m * HID + 32 + c];
        sSc[id] = s;
    }
    __syncthreads();

    // ---- GJ2: Scinv (wave 0, lanes 0-31) ----
    if (wave == 0 && lane < 32) {
        float w[32], wi[32];
        #pragma unroll
        for (int c = 0; c < 32; ++c) {
            w[c]  = sSc[lane * 32 + c];
            wi[c] = (c == lane) ? 1.0f : 0.0f;
        }
        bool used = false; int myk = 0;
        #pragma unroll
        for (int k = 0; k < 32; ++k) {
            float a_rk = w[k];
            float v = used ? -1.0f : fabsf(a_rk);
            int idx = lane;
            #pragma unroll
            for (int off = 16; off; off >>= 1) {
                float v2 = __shfl_down(v, off, 32);
                int   i2 = __shfl_down(idx, off, 32);
                if (v2 > v) { v = v2; idx = i2; }
            }
            int p = __shfl(idx, 0, 32);
            float piv = RDLANE(a_rk, p);
            float rp  = 1.0f / piv;
            bool isp  = (lane == p);
            float coeff = isp ? rp : -(a_rk * rp);
            if (isp) { used = true; myk = k; }
            #pragma unroll
            for (int c = k + 1; c < 32; ++c) {
                float tmp = RDLANE(w[c], p);
                w[c] = fmaf(tmp, coeff, isp ? 0.0f : w[c]);
            }
            #pragma unroll
            for (int c = 0; c < 32; ++c) {
                float tmp = RDLANE(wi[c], p);
                wi[c] = fmaf(tmp, coeff, isp ? 0.0f : wi[c]);
            }
        }
        #pragma unroll
        for (int c = 0; c < 32; ++c) sScinv[myk * 32 + c] = wi[c];
    }
    __syncthreads();

    // ---- X1 = Scinv*W ; X2 = V*Scinv ----
    for (int id = tid; id < 2048; id += 512) {
        int sel = id >> 10, rc = id & 1023, r = rc >> 5, c = rc & 31;
        float s = 0.f;
        if (sel == 0) {
            for (int m = 0; m < 32; ++m) s += sScinv[r * 32 + m] * sW[m * 32 + c];
            sX1[rc] = s;
        } else {
            for (int m = 0; m < 32; ++m) s += sV[r * 32 + m] * sScinv[m * 32 + c];
            sX2[rc] = s;
        }
    }
    __syncthreads();

    // ---- assemble T1inv (X3 = V*X1 fused into top-left) ----
    for (int id = tid; id < 1024; id += 512) {
        int r = id >> 5, c = id & 31;
        float x3 = 0.f;
        for (int m = 0; m < 32; ++m) x3 += sV[r * 32 + m] * sX1[m * 32 + c];
        ws[OFF_T1INV + r * 64 + c]              = sPinv[id] + x3;
        ws[OFF_T1INV + r * 64 + 32 + c]         = -sX2[id];
        ws[OFF_T1INV + (32 + r) * 64 + c]       = -sX1[id];
        ws[OFF_T1INV + (32 + r) * 64 + 32 + c]  = sScinv[id];
    }
    __syncthreads();

    // ---- constant-matrix tail (round-7 proven k_small body, verbatim) ----
    for (int id = tid; id < 64 * 20; id += 512) {
        int r = id / 20, j = id % 20;
        float s = 0.f;
        const float* tr = ws + OFF_T1INV + r * 64;
        for (int c = 0; c < 64; ++c) s += tr[c] * C[c * HID + 64 + j];
        Xs[r][j] = s;
        ws[OFF_XT + j * 64 + r] = s;
    }
    __syncthreads();
    for (int id = tid; id < HID * 20; id += 512) {
        int p = id / 20, j = id % 20;
        float v = (p < 64) ? -Xs[p][j] : ((p - 64) == j ? 1.f : 0.f);
        Ns[p][j] = v;
        ws[OFF_N + id] = v;
    }
    __syncthreads();
    for (int id = tid; id < HID * 20; id += 512) {
        int p = id / 20, j = id % 20;
        float s = 0.f;
        for (int m = 0; m < HID; ++m) s += A[p * HID + m] * Ns[m][j];
        ANs[p][j] = s;
        ws[OFF_AN + id] = s;
    }
    __syncthreads();
    for (int id = tid; id < 400; id += 512) {
        int a = id / 20, b = id % 20;
        float sn = 0.f, sf = 0.f, sg = 0.f;
        for (int p = 0; p < HID; ++p) {
            sn += Ns[p][a] * Ns[p][b];
            sf += Ns[p][a] * ANs[p][b];
            sg += ANs[p][a] * ANs[p][b];
        }
        ws[OFF_F + id]     = sf;
        ws[OFF_D + id]     = sn + sg;
        ws[OFF_DLAST + id] = sn;
    }
    for (int id = tid; id < 20 * 64; id += 512) {
        int j = id / 64, c = id % 64;
        float s1 = 0.f, s2 = 0.f;
        for (int p = 0; p < HID; ++p) {
            float av = A[p * HID + c];
            s1 += Ns[p][j] * av;
            s2 += ANs[p][j] * av;
        }
        ws[OFF_NA1 + id]  = s1;
        ws[OFF_ANA1 + id] = s2;
        ws[OFF_ANT1 + id] = ANs[c][j];
    }
}

// ---------------------------------------------------------------------------
// k_factor (proven, verbatim)
// ---------------------------------------------------------------------------
__global__ __launch_bounds__(64, 1) void k_factor(float* __restrict__ ws) {
    __shared__ float sD[400], sDl[400], sF[400];
    int lane = threadIdx.x;
    for (int id = lane; id < 400; id += 64) {
        sD[id]  = ws[OFF_D + id];
        sDl[id] = ws[OFF_DLAST + id];
        sF[id]  = ws[OFF_F + id];
    }
    __syncthreads();

    float* Jg = ws + OFF_JG;
    float* Zg = ws + OFF_ZG;

    float Kprev[20];
    #pragma unroll
    for (int r = 0; r < 20; ++r) Kprev[r] = 0.f;
    int iconv = 62;
    for (int i = 0; i < 64; ++i) {
        bool last = (i == 63);
        float w[40];
        #pragma unroll
        for (int r = 0; r < 20; ++r) {
            float v, v2 = 0.f;
            if (lane < 20) {
                float dv = last ? sDl[r * 20 + lane] : sD[r * 20 + lane];
                v  = dv - Kprev[r];
                v2 = sF[r * 20 + lane];
            } else if (lane < 40) {
                v = sF[(lane - 20) * 20 + r];          // F^T block
            } else if (lane < 60) {
                v = (r == lane - 40) ? 1.f : 0.f;      // I block
            } else {
                v = 0.f;
            }
            w[r]      = v;
            w[20 + r] = v2;                             // [F 0 0]
        }
        #pragma unroll
        for (int k = 0; k < 20; ++k) {
            float rp = __builtin_amdgcn_rcpf(RDLANE(w[k], k));
            w[k] *= rp;
            #pragma unroll
            for (int r = 0; r < 40; ++r) {
                if (r == k) continue;
                float ck = RDLANE(w[r], k);
                w[r] -= ck * w[k];
            }
        }
        if (lane >= 40 && lane < 60) {
            int c = lane - 40;
            #pragma unroll
            for (int r = 0; r < 20; ++r) {
                Jg[i * 400 + r * 20 + c] = w[r];                   // J row-major
                if (!last) Zg[i * 400 + c * 20 + r] = -w[20 + r];  // Z = (FJ)^T
            }
        }
        if (last) break;
        float dmax = 0.f, kmax = 0.f;
        int gsel = (20 + lane) << 2;
        #pragma unroll
        for (int r = 0; r < 20; ++r) {
            float kn = -__uint_as_float(__builtin_amdgcn_ds_bpermute(
                gsel, (int)__float_as_uint(w[20 + r])));
            dmax = fmaxf(dmax, fabsf(kn - Kprev[r]));
            kmax = fmaxf(kmax, fabsf(kn));
            Kprev[r] = kn;
        }
        if (i < 62 && __all((lane >= 20) || (dmax <= 1e-7f + 1e-4f * kmax))) {
            iconv = i;
            i = 62;            // next loop iteration is the terminal (63)
        }
    }
    if (lane == 0) ws[OFF_ICONV] = __int_as_float(iconv);
}

// ---------------------------------------------------------------------------
// k_qg (proven, verbatim)
// ---------------------------------------------------------------------------
__global__ __launch_bounds__(64) void k_qg(const float* __restrict__ x,
                                           float* __restrict__ ws) {
    int i = blockIdx.x, b = blockIdx.y, r = threadIdx.x;
    __shared__ float yv[3][64];
    __shared__ float qs[3][64];
    yv[1][r] = x[(b * TT + i) * 64 + r];
    yv[0][r] = (i > 0)  ? x[(b * TT + i - 1) * 64 + r] : 0.f;
    yv[2][r] = (i < 63) ? x[(b * TT + i + 1) * 64 + r] : 0.f;
    __syncthreads();
    const float* Ti = ws + OFF_T1INV + r * 64;
    float q0 = 0.f, q1 = 0.f, q2 = 0.f;
    for (int c = 0; c < 64; ++c) {
        float t = Ti[c];
        q0 += t * yv[0][c];
        q1 += t * yv[1][c];
        q2 += t * yv[2][c];
    }
    qs[0][r] = q0; qs[1][r] = q1; qs[2][r] = q2;
    ws[OFF_Q + (b * TT + i) * 64 + r] = q1;
    __syncthreads();
    if (r < 20) {
        const float* xt = ws + OFF_XT   + r * 64;
        const float* na = ws + OFF_NA1  + r * 64;
        const float* at = ws + OFF_ANT1 + r * 64;
        const float* aa = ws + OFF_ANA1 + r * 64;
        float s = 0.f;
        if (i < 63) {
            for (int c = 0; c < 64; ++c)
                s += xt[c] * qs[1][c] + na[c] * qs[0][c] + at[c] * qs[2][c] - aa[c] * qs[1][c];
        } else {
            for (int c = 0; c < 64; ++c)
                s += xt[c] * qs[1][c] + na[c] * qs[0][c];
        }
        ws[OFF_G + (i * 16 + b) * 20 + r] = s;
    }
}

// ---------------------------------------------------------------------------
// k_sweeps (proven, verbatim)
// ---------------------------------------------------------------------------
__global__ __launch_bounds__(64, 1) void k_sweeps(float* __restrict__ ws) {
    __shared__ float rh[TT][2][20];   // r~ history per batch-half
    __shared__ float th[2][20];       // rolling t
    int lane = threadIdx.x;
    int bh   = lane >> 5;
    int b    = (blockIdx.x << 1) + bh;
    int j    = lane & 31;
    int jj   = (j < 20) ? j : 0;
    bool actj = (j < 20);

    int icv = __float_as_int(ws[OFF_ICONV]);
    const float* G  = ws + OFF_G;
    const float* Jg = ws + OFF_JG;
    const float* Zg = ws + OFF_ZG;
    float* TS = ws + OFF_TS;

    float Mrow[20];                       // FJ_infty row jj = Z_infty col jj
    #pragma unroll
    for (int m = 0; m < 20; ++m) Mrow[m] = Zg[icv * 400 + m * 20 + jj];
    float Jr[20], Zr[20], J63r[20];
    ld20(Jg + icv * 400 + jj * 20, Jr);
    ld20(Zg + icv * 400 + jj * 20, Zr);
    ld20(Jg + 63 * 400 + jj * 20, J63r);

    float rt = 0.f, gnext = 0.f;
    if (actj) {
        rt    = G[(0 * 16 + b) * 20 + j];
        rh[0][bh][j] = rt;
        gnext = G[(1 * 16 + b) * 20 + j];
    }
    for (int i = 1; i < TT; ++i) {
        float rv[20];
        ld20(&rh[i - 1][bh][0], rv);
        float s;
        if (i - 1 < icv) {
            float fr[20];
            #pragma unroll
            for (int m = 0; m < 20; ++m) fr[m] = Zg[(i - 1) * 400 + m * 20 + jj];
            s = gnext + dot20(fr, rv);
        } else {
            s = gnext + dot20(Mrow, rv);
        }
        rt = s;
        if (actj) {
            rh[i][bh][j] = rt;
            gnext = (i + 1 < TT) ? G[((i + 1) * 16 + b) * 20 + j] : 0.f;
        }
    }

    {
        float rv[20];
        ld20(&rh[63][bh][0], rv);
        float tn = dot20(J63r, rv);
        if (actj) {
            TS[(63 * 16 + b) * 20 + j] = tn;
            th[bh][j] = tn;
        }
        for (int i = 62; i >= 0; --i) {
            float rvi[20], tv[20];
            ld20(&rh[i][bh][0], rvi);
            ld20(&th[bh][0], tv);
            float t;
            if (i < icv) {
                float jr[20], zr[20];
                ld20(Jg + i * 400 + jj * 20, jr);
                ld20(Zg + i * 400 + jj * 20, zr);
                t = dot20(jr, rvi) + dot20(zr, tv);
            } else {
                t = dot20(Jr, rvi) + dot20(Zr, tv);
            }
            if (actj) {
                TS[(i * 16 + b) * 20 + j] = t;
                th[bh][j] = t;
            }
        }
    }
}

// ---------------------------------------------------------------------------
// k_loss (proven, verbatim)
// ---------------------------------------------------------------------------
__global__ __launch_bounds__(128) void k_loss(const float* __restrict__ A,
                                              float* __restrict__ ws) {
    int i = blockIdx.x + 1, b = blockIdx.y, tid = threadIdx.x;
    __shared__ float ti[20], tm[20], qi[64], qm[64];
    __shared__ float red[128];
    if (tid < 20) {
        ti[tid] = ws[OFF_TS + (i * 16 + b) * 20 + tid];
        tm[tid] = ws[OFF_TS + ((i - 1) * 16 + b) * 20 + tid];
    }
    if (tid < 64) {
        qi[tid] = ws[OFF_Q + (b * TT + i) * 64 + tid];
        qm[tid] = ws[OFF_Q + (b * TT + i - 1) * 64 + tid];
    }
    __syncthreads();
    float e = 0.f;
    if (tid < HID) {
        int p = tid;
        float s = (p < 64) ? qi[p] : 0.f;
        const float* Np  = ws + OFF_N  + p * 20;
        const float* ANp = ws + OFF_AN + p * 20;
        for (int j = 0; j < 20; ++j) s += Np[j] * ti[j] - ANp[j] * tm[j];
        const float* Ar = A + p * HID;
        for (int c = 0; c < 64; ++c) s -= Ar[c] * qm[c];
        e = s * s;
    }
    red[tid] = e;
    __syncthreads();
    for (int off = 64; off; off >>= 1) {
        if (tid < off) red[tid] += red[tid + off];
        __syncthreads();
    }
    if (tid == 0) ws[OFF_PART + b * 63 + (i - 1)] = red[0];
}

// ---------------------------------------------------------------------------
// k_reduce (proven, verbatim)
// ---------------------------------------------------------------------------
__global__ __launch_bounds__(256) void k_reduce(const float* __restrict__ ws,
                                                float* __restrict__ out) {
    __shared__ float red[256];
    int tid = threadIdx.x;
    float s = 0.f;
    for (int id = tid; id < BB * 63; id += 256) s += ws[OFF_PART + id];
    red[tid] = s;
    __syncthreads();
    for (int off = 128; off; off >>= 1) {
        if (tid < off) red[tid] += red[tid + off];
        __syncthreads();
    }
    if (tid == 0) out[0] = red[0] / (float)(BB * (TT - 1) * HID);
}

extern "C" void kernel_launch(void* const* d_in, const int* in_sizes, int n_in,
                              void* d_out, int out_size, void* d_ws, size_t ws_size,
                              hipStream_t stream) {
    (void)in_sizes; (void)n_in; (void)out_size; (void)ws_size;
    const float* x = (const float*)d_in[0];
    const float* A = (const float*)d_in[1];
    const float* C = (const float*)d_in[2];
    float* ws  = (float*)d_ws;
    float* out = (float*)d_out;

    k_prep  <<<dim3(1),          dim3(512), 0, stream>>>(A, C, ws);
    k_factor<<<dim3(1),          dim3(64),  0, stream>>>(ws);
    k_qg    <<<dim3(TT, BB),     dim3(64),  0, stream>>>(x, ws);
    k_sweeps<<<dim3(8),          dim3(64),  0, stream>>>(ws);
    k_loss  <<<dim3(TT - 1, BB), dim3(128), 0, stream>>>(A, ws);
    k_reduce<<<dim3(1),          dim3(256), 0, stream>>>(ws, out);
}